// Round 1
// baseline (39217.700 us; speedup 1.0000x reference)
//
#include <hip/hip_runtime.h>
#include <hip/hip_cooperative_groups.h>

namespace cg = cooperative_groups;

#define NB 512   // batch
#define NIN 64   // input features
#define NH 256   // hidden
#define NT 200   // timesteps
#define NO 2     // outputs

struct Params {
  const float* input; const float* x_mean;
  const float* w_dg_x; const float* b_dg_x;
  const float* w_dg_h; const float* b_dg_h;
  const float* w_xz; const float* w_hz; const float* w_mz; const float* b_z;
  const float* w_xr; const float* w_hr; const float* w_mr; const float* b_r;
  const float* w_xh; const float* w_hh; const float* w_mh; const float* b_h;
  const float* bn_gamma; const float* bn_beta;
  float* out_h; float* out_x;
  float* hdec; float* rh; float* xlast; float* part;
  const float* Xt; const float* Mt; const float* Dt; float* xs;
  int fast;
};

__device__ __forceinline__ float sigm(float x){ return 1.f/(1.f+__expf(-x)); }
__device__ __forceinline__ float tanh_fast(float x){ return 2.f/(1.f+__expf(-2.f*x)) - 1.f; }
__device__ __forceinline__ float wred(float v){
#pragma unroll
  for (int off=32; off>0; off>>=1) v += __shfl_xor(v, off, 64);
  return v;
}

// Compute x_imp[t][i0][:] for the 64 rows of this wave (lane = row). Called by wave 0 of each block.
__device__ __forceinline__ void do_ximp(const Params& p, int t, int i0, int b){
  const float* dp; const float* xq; const float* mq; int as;
  if (p.fast){
    size_t base = (size_t)t*NIN*NB;
    dp = p.Dt + base + b; xq = p.Xt + base + (size_t)i0*NB + b; mq = p.Mt + base + (size_t)i0*NB + b; as = NB;
  } else {
    size_t bb = (size_t)b*3*NIN*NT;
    dp = p.input + bb + 2*(size_t)NIN*NT + t;
    xq = p.input + bb + (size_t)i0*NT + t;
    mq = p.input + bb + (size_t)NIN*NT + (size_t)i0*NT + t;
    as = NT;
  }
  float gx = p.b_dg_x[i0];
  const float* Wdx = p.w_dg_x + i0*NIN;
#pragma unroll 8
  for (int i=0;i<NIN;i++) gx = fmaf(dp[(size_t)i*as], Wdx[i], gx);
  gx = __expf(-fmaxf(gx, 0.f));
  float x = *xq, m = *mq;
  float xl = (t==0) ? 0.f : p.xlast[i0*NB + b];
  xl = (m > 0.f) ? x : xl;
  p.xlast[i0*NB + b] = xl;
  float xi = m*x + (1.f-m)*(gx*xl + (1.f-gx)*p.x_mean[i0]);
  if (p.fast) p.xs[(size_t)t*NIN*NB + (size_t)i0*NB + b] = xi;
  else        p.out_x[(size_t)b*NIN*NT + (size_t)i0*NT + t] = xi;
}

// Persistent cooperative kernel: grid 512 = 8 row-groups x 64 j-quads; block 256 = 4 waves.
// wave w of block (bi,jq) owns hidden unit j = jq*4+w for rows b = bi*64 + lane.
__global__ __launch_bounds__(256, 2) void grud_main(Params p){
  const int tid  = threadIdx.x;
  const int lane = tid & 63;
  const int wv   = __builtin_amdgcn_readfirstlane(tid >> 6);
  const int blk  = blockIdx.x;
  const int bi   = blk >> 6;      // 0..7  (64 rows each)
  const int jq   = blk & 63;      // 0..63 (4 hidden units each)
  const int j    = (jq<<2) + wv;  // wave-uniform hidden unit
  const int b    = (bi<<6) + lane;
  cg::grid_group gg = cg::this_grid();
  __shared__ float sh[64][4];

  // wave-uniform weight row bases (scalar loads expected)
  const float* Wxz = p.w_xz + j*NIN; const float* Wxr = p.w_xr + j*NIN; const float* Wxh = p.w_xh + j*NIN;
  const float* Wmz = p.w_mz + j*NIN; const float* Wmr = p.w_mr + j*NIN; const float* Wmh = p.w_mh + j*NIN;
  const float* Whz = p.w_hz + j*NH;  const float* Whr = p.w_hr + j*NH;  const float* Whh = p.w_hh + j*NH;
  const float* Wdh = p.w_dg_h + j*NIN;

  // prologue: h_dec(0) = gamma_h*h0 = 0 ; x_imp(0)
  p.hdec[blk*256 + tid] = 0.f;
  if (wv == 0) do_ximp(p, 0, jq, b);
  gg.sync();

  for (int t=0; t<NT; ++t){
    // activation stream pointers for this t
    const float* xp; const float* mp; int as;
    if (p.fast){ xp = p.xs + (size_t)t*NIN*NB + b; mp = p.Mt + (size_t)t*NIN*NB + b; as = NB; }
    else { xp = p.out_x + (size_t)b*NIN*NT + t; mp = p.input + ((size_t)b*3+1)*NIN*NT + t; as = NT; }

    // ---------- P1: z, r (and x/m contribution to h_tilde) ----------
    float zacc = p.b_z[j], racc = p.b_r[j], xmh = 0.f;
#pragma unroll 4
    for (int i=0;i<NIN;i++){
      float xi = xp[(size_t)i*as], mi = mp[(size_t)i*as];
      zacc = fmaf(xi, Wxz[i], zacc); racc = fmaf(xi, Wxr[i], racc);
      zacc = fmaf(mi, Wmz[i], zacc); racc = fmaf(mi, Wmr[i], racc);
      xmh  = fmaf(xi, Wxh[i], xmh);  xmh  = fmaf(mi, Wmh[i], xmh);
    }
    {
      const float* hp = p.hdec + b;
#pragma unroll 8
      for (int k=0;k<NH;k++){
        float hd = hp[(size_t)k*NB];
        zacc = fmaf(hd, Whz[k], zacc); racc = fmaf(hd, Whr[k], racc);
      }
    }
    float hd_own = p.hdec[(size_t)j*NB + b];
    float z = sigm(zacc), r = sigm(racc);
    p.rh[(size_t)j*NB + b] = r * hd_own;
    gg.sync();

    // ---------- P2: h_tilde, h_pre, BN partial sums ----------
    float hacc = p.b_h[j] + xmh;
    {
      const float* rp = p.rh + b;
#pragma unroll 8
      for (int k=0;k<NH;k++) hacc = fmaf(rp[(size_t)k*NB], Whh[k], hacc);
    }
    float ht   = tanh_fast(hacc);
    float hpre = (1.f - z)*hd_own + z*ht;
    float s1 = wred(hpre);
    float s2 = wred(hpre*hpre);
    if (lane == 0){
      int pb = ((t&1)*NH + j)*16 + bi*2;
      p.part[pb] = s1; p.part[pb+1] = s2;
    }
    gg.sync();

    // ---------- P3: BN finalize, write hidden, prep t+1 ----------
    float S1 = 0.f, S2 = 0.f;
    {
      int pb = ((t&1)*NH + j)*16;
#pragma unroll
      for (int g=0; g<8; ++g){ S1 += p.part[pb+g*2]; S2 += p.part[pb+g*2+1]; }
    }
    float mu  = S1*(1.f/NB);
    float var = S2*(1.f/NB) - mu*mu;
    float a   = p.bn_gamma[j]*rsqrtf(var + 1e-5f);
    float c   = p.bn_beta[j] - a*mu;
    float hbn = fmaf(a, hpre, c);

    // staged coalesced-ish hidden write (float4 per row)
    sh[lane][wv] = hbn;
    __syncthreads();
    if (tid < 64){
      float4 v = *reinterpret_cast<const float4*>(&sh[tid][0]);
      *reinterpret_cast<float4*>(p.out_h + (size_t)(bi*64+tid)*NT*NH + (size_t)t*NH + (jq<<2)) = v;
    }

    if (t < NT-1){
      const float* dp; int das;
      if (p.fast){ dp = p.Dt + (size_t)(t+1)*NIN*NB + b; das = NB; }
      else { dp = p.input + ((size_t)b*3+2)*NIN*NT + (t+1); das = NT; }
      float gh = p.b_dg_h[j];
#pragma unroll 8
      for (int i=0;i<NIN;i++) gh = fmaf(dp[(size_t)i*das], Wdh[i], gh);
      gh = __expf(-fmaxf(gh, 0.f));
      p.hdec[(size_t)j*NB + b] = gh * hbn;
      if (wv == 0) do_ximp(p, t+1, jq, b);
    }
    gg.sync();
  }
}

// y[b][t][o] = sigmoid(h[b][t][:] . w_hy[o][:] + b_hy[o]) ; one wave per (b,t)
__global__ void k_y(const float* __restrict__ h, const float* __restrict__ w_hy,
                    const float* __restrict__ b_hy, float* __restrict__ y){
  int lane = threadIdx.x & 63;
  int gid  = blockIdx.x*4 + (threadIdx.x>>6);   // 0 .. NB*NT-1
  int b = gid / NT, t = gid % NT;
  const float* hp = h + (size_t)b*NT*NH + (size_t)t*NH + lane;
  float a0=0.f, a1=0.f;
#pragma unroll
  for (int m=0;m<4;m++){
    float hv = hp[m*64];
    a0 = fmaf(hv, w_hy[lane + m*64], a0);
    a1 = fmaf(hv, w_hy[NH + lane + m*64], a1);
  }
  a0 = wred(a0); a1 = wred(a1);
  if (lane == 0){
    y[(size_t)b*NT*NO + t*NO + 0] = sigm(a0 + b_hy[0]);
    y[(size_t)b*NT*NO + t*NO + 1] = sigm(a1 + b_hy[1]);
  }
}

// transpose input (B,3,IN,T) -> [c][t][i][b]
__global__ void k_tin(const float* __restrict__ in, float* __restrict__ dst){
  int idx = blockIdx.x;
  int tt4 = idx & 3; int bt = (idx>>2) & 7; int i = (idx>>5) & 63; int c = idx>>11;
  __shared__ float ld[64][65];
  int lane = threadIdx.x & 63, sub = threadIdx.x >> 6;
  int t0 = tt4*64, b0 = bt*64;
  for (int r=sub; r<64; r+=4){
    int t = t0 + lane;
    if (t < NT) ld[r][lane] = in[(((size_t)(b0+r)*3 + c)*NIN + i)*NT + t];
  }
  __syncthreads();
  for (int r=sub; r<64; r+=4){
    int t = t0 + r;
    if (t < NT) dst[(size_t)c*NT*NIN*NB + (size_t)t*NIN*NB + (size_t)i*NB + b0 + lane] = ld[lane][r];
  }
}

// xs [t][i][b] -> out_x (B,IN,T)
__global__ void k_tx(const float* __restrict__ xs, float* __restrict__ out_x){
  int idx = blockIdx.x;
  int tt4 = idx & 3; int bt = (idx>>2)&7; int i = idx>>5;
  __shared__ float ld[64][65];
  int lane = threadIdx.x & 63, sub = threadIdx.x>>6;
  int t0 = tt4*64, b0 = bt*64;
  for (int r=sub; r<64; r+=4){
    int t = t0 + r;
    if (t < NT) ld[r][lane] = xs[(size_t)t*NIN*NB + (size_t)i*NB + b0 + lane];
  }
  __syncthreads();
  for (int r=sub; r<64; r+=4){
    int t = t0 + lane;
    if (t < NT) out_x[(size_t)(b0+r)*NIN*NT + (size_t)i*NT + t] = ld[lane][r];
  }
}

__global__ void k_mask(const float* __restrict__ in, float* __restrict__ om){
  int b = blockIdx.x;
  const float4* src = reinterpret_cast<const float4*>(in + ((size_t)b*3+1)*NIN*NT);
  float4* dst = reinterpret_cast<float4*>(om + (size_t)b*NIN*NT);
  for (int r = threadIdx.x; r < NIN*NT/4; r += 256) dst[r] = src[r];
}

extern "C" void kernel_launch(void* const* d_in, const int* in_sizes, int n_in,
                              void* d_out, int out_size, void* d_ws, size_t ws_size,
                              hipStream_t stream){
  (void)in_sizes; (void)n_in; (void)out_size;
  Params p;
  p.input = (const float*)d_in[0];  p.x_mean = (const float*)d_in[1];
  p.w_dg_x = (const float*)d_in[2]; p.b_dg_x = (const float*)d_in[3];
  p.w_dg_h = (const float*)d_in[4]; p.b_dg_h = (const float*)d_in[5];
  p.w_xz = (const float*)d_in[6];   p.w_hz = (const float*)d_in[7];
  p.w_mz = (const float*)d_in[8];   p.b_z  = (const float*)d_in[9];
  p.w_xr = (const float*)d_in[10];  p.w_hr = (const float*)d_in[11];
  p.w_mr = (const float*)d_in[12];  p.b_r  = (const float*)d_in[13];
  p.w_xh = (const float*)d_in[14];  p.w_hh = (const float*)d_in[15];
  p.w_mh = (const float*)d_in[16];  p.b_h  = (const float*)d_in[17];
  const float* w_hy = (const float*)d_in[18];
  const float* b_hy = (const float*)d_in[19];
  p.bn_gamma = (const float*)d_in[20]; p.bn_beta = (const float*)d_in[21];

  float* out = (float*)d_out;
  float* out_y = out;
  p.out_h = out + (size_t)NB*NT*NO;
  p.out_x = p.out_h + (size_t)NB*NT*NH;
  float* out_m = p.out_x + (size_t)NB*NIN*NT;

  float* ws = (float*)d_ws;
  p.hdec  = ws;
  p.rh    = ws + (size_t)NH*NB;
  p.xlast = ws + (size_t)2*NH*NB;
  p.part  = ws + (size_t)2*NH*NB + NIN*NB;
  size_t small = (size_t)2*NH*NB + NIN*NB + 2*NH*8*2;
  size_t big   = (size_t)4*NT*NIN*NB;
  p.fast = (ws_size >= (small + big)*sizeof(float)) ? 1 : 0;
  float* Xt = ws + small;
  p.Xt = Xt;
  p.Mt = Xt + (size_t)NT*NIN*NB;
  p.Dt = Xt + (size_t)2*NT*NIN*NB;
  p.xs = Xt + (size_t)3*NT*NIN*NB;

  if (p.fast) hipLaunchKernelGGL(k_tin, dim3(6144), dim3(256), 0, stream, p.input, Xt);

  void* args[] = { &p };
  hipLaunchCooperativeKernel(grud_main, dim3(512), dim3(256), args, 0, stream);

  hipLaunchKernelGGL(k_y,   dim3(NB*NT/4), dim3(256), 0, stream, p.out_h, w_hy, b_hy, out_y);
  if (p.fast) hipLaunchKernelGGL(k_tx, dim3(2048), dim3(256), 0, stream, p.xs, p.out_x);
  hipLaunchKernelGGL(k_mask, dim3(NB), dim3(256), 0, stream, p.input, out_m);
}

// Round 2
// 5938.438 us; speedup vs baseline: 6.6040x; 6.6040x over previous
//
#include <hip/hip_runtime.h>

#define NB 512
#define NIN 64
#define NH 256
#define NT 200
#define NO 2
#define NBI (NB*NIN)    // 32768  one [i][b] plane
#define NBH (NB*NH)     // 131072 one [k][b] plane

__device__ __forceinline__ float sigm(float x){ return 1.f/(1.f+__expf(-x)); }
__device__ __forceinline__ float tanh_fast(float x){ return 2.f/(1.f+__expf(-2.f*x)) - 1.f; }
__device__ __forceinline__ float wred(float v){
#pragma unroll
  for (int off=32; off>0; off>>=1) v += __shfl_xor(v, off, 64);
  return v;
}

// ---------------- init: zero hdec ----------------
__global__ void k_init(float* __restrict__ hdec){
  int i = blockIdx.x*256 + threadIdx.x;
  if (i < NBH) hdec[i] = 0.f;
}

// ---------------- one-time weight transposes ----------------
// Wgt[k][io] io in 0..319 (0..63 = w_dg_x rows, 64..319 = w_dg_h rows), k in 0..63
// W2t[k][jo] jo in 0..767 (z,r,h stacked), k in 0..127 (x-part 0..63, m-part 64..127)
__global__ void k_wprep(const float* __restrict__ w_dg_x, const float* __restrict__ w_dg_h,
                        const float* __restrict__ w_xz, const float* __restrict__ w_xr, const float* __restrict__ w_xh,
                        const float* __restrict__ w_mz, const float* __restrict__ w_mr, const float* __restrict__ w_mh,
                        float* __restrict__ Wgt, float* __restrict__ W2t){
  int idx = blockIdx.x*256 + threadIdx.x;
  if (idx < 320*64){
    int io = idx % 320, k = idx / 320;
    Wgt[k*320 + io] = (io < 64) ? w_dg_x[io*NIN + k] : w_dg_h[(io-64)*NIN + k];
  } else if (idx < 320*64 + 768*128){
    int j2 = idx - 320*64;
    int jo = j2 % 768, k = j2 / 768;
    int mi = jo >> 8, jr = jo & 255;
    const float* WX = (mi==0)? w_xz : (mi==1)? w_xr : w_xh;
    const float* WM = (mi==0)? w_mz : (mi==1)? w_mr : w_mh;
    W2t[k*768 + jo] = (k < 64) ? WX[jr*NIN + k] : WM[jr*NIN + (k-64)];
  }
}

// ---------------- input transpose: (B,3,IN,T) slice -> [t'][i][b] ----------------
__global__ __launch_bounds__(256) void k_tin(const float* __restrict__ in,
    float* __restrict__ Xt, float* __restrict__ Mt, float* __restrict__ Dt,
    int C, int TT, int c0){
  __shared__ float ld[64][65];
  int idx = blockIdx.x;
  int tt = idx % TT; int bt = (idx/TT) & 7; int i = (idx/(TT*8)) & 63; int c = idx/(TT*8*64);
  float* dst = (c==0)? Xt : (c==1)? Mt : Dt;
  int lane = threadIdx.x & 63, sub = threadIdx.x >> 6;
  int t0 = tt*64, b0 = bt*64;
  for (int r = sub; r < 64; r += 4){
    int tp = t0 + lane;
    if (tp < C) ld[r][lane] = in[((size_t)(b0+r)*3 + c)*NIN*NT + (size_t)i*NT + c0 + tp];
  }
  __syncthreads();
  for (int r = sub; r < 64; r += 4){
    int tp = t0 + r;
    if (tp < C) dst[(size_t)tp*NBI + i*NB + b0 + lane] = ld[lane][r];
  }
}

// ---------------- G1: gamma GEMM. out = exp(-relu(W*d + bias)) ----------------
// grid: C*40 blocks, block 256 (16x16), tile 64io x 64b, k=64
__global__ __launch_bounds__(256) void k_g1(const float* __restrict__ Wgt, const float* __restrict__ Dt,
    const float* __restrict__ b_dg_x, const float* __restrict__ b_dg_h,
    float* __restrict__ gx, float* __restrict__ gh){
  __shared__ float Wl[64*64];   // [k][io]
  __shared__ float Dl[64*64];   // [k][b]
  int idx = blockIdx.x;
  int bt = idx & 7, io5 = (idx>>3) % 5, tp = idx / 40;
  int b0 = bt*64, io0 = io5*64;
  int tid = threadIdx.x, tx = tid & 15, ty = tid >> 4;
  for (int f = tid; f < 1024; f += 256){
    int k = f >> 4, seg = f & 15;
    *(float4*)&Wl[k*64 + seg*4] = *(const float4*)&Wgt[k*320 + io0 + seg*4];
    *(float4*)&Dl[k*64 + seg*4] = *(const float4*)&Dt[(size_t)tp*NBI + k*NB + b0 + seg*4];
  }
  __syncthreads();
  float acc[4][4] = {};
#pragma unroll 4
  for (int k = 0; k < 64; k++){
    float av[4], bv[4];
#pragma unroll
    for (int e = 0; e < 4; e++){ av[e] = Wl[k*64 + ty + e*16]; bv[e] = Dl[k*64 + tx + e*16]; }
#pragma unroll
    for (int e2 = 0; e2 < 4; e2++)
#pragma unroll
      for (int e = 0; e < 4; e++) acc[e2][e] = fmaf(av[e2], bv[e], acc[e2][e]);
  }
#pragma unroll
  for (int e2 = 0; e2 < 4; e2++){
    int io = io0 + ty + e2*16;
    float bias = (io < 64) ? b_dg_x[io] : b_dg_h[io-64];
#pragma unroll
    for (int e = 0; e < 4; e++){
      float v = __expf(-fmaxf(acc[e2][e] + bias, 0.f));
      int b = b0 + tx + e*16;
      if (io < 64) gx[(size_t)tp*NBI + io*NB + b] = v;
      else         gh[(size_t)tp*NBH + (size_t)(io-64)*NB + b] = v;
    }
  }
}

// ---------------- imputation scan over chunk ----------------
__global__ void k_scan(const float* __restrict__ Xt, const float* __restrict__ Mt,
                       const float* __restrict__ gx, const float* __restrict__ x_mean,
                       float* __restrict__ xlast, float* __restrict__ ximp, int C, int first){
  int gi = blockIdx.x*256 + threadIdx.x;   // 32768 threads = [i][b]
  int i = gi >> 9;
  float xl = first ? 0.f : xlast[gi];
  float xm = x_mean[i];
  for (int t = 0; t < C; t++){
    size_t o = (size_t)t*NBI + gi;
    float x = Xt[o], m = Mt[o], g = gx[o];
    xl = (m > 0.f) ? x : xl;
    ximp[o] = m*x + (1.f-m)*(g*xl + (1.f-g)*xm);
  }
  xlast[gi] = xl;
}

// ---------------- G2: Xzrh GEMM. Xzrh[t'][jo][b] = W2*[ximp;m] + bias ----------------
// grid: C*96 blocks, block 256 (16x16), tile 64jo x 64b, k=128
__global__ __launch_bounds__(256) void k_g2(const float* __restrict__ W2t, const float* __restrict__ ximp,
    const float* __restrict__ Mt, const float* __restrict__ bz, const float* __restrict__ br,
    const float* __restrict__ bh, float* __restrict__ Xzrh){
  __shared__ float smem[16384];             // Wl[128][64] + Al[128][64] = 64KB
  float* Wl = smem; float* Al = smem + 8192;
  int idx = blockIdx.x;
  int bt = idx & 7, jt = (idx>>3) % 12, tp = idx / 96;
  int b0 = bt*64, jo0 = jt*64, mi = jt >> 2;
  int tid = threadIdx.x, tx = tid & 15, ty = tid >> 4;
  for (int f = tid; f < 2048; f += 256){
    int k = f >> 4, seg = f & 15;
    *(float4*)&Wl[k*64 + seg*4] = *(const float4*)&W2t[k*768 + jo0 + seg*4];
    const float* src = (k < 64) ? (ximp + (size_t)tp*NBI + k*NB) : (Mt + (size_t)tp*NBI + (size_t)(k-64)*NB);
    *(float4*)&Al[k*64 + seg*4] = *(const float4*)&src[b0 + seg*4];
  }
  __syncthreads();
  float acc[4][4] = {};
#pragma unroll 4
  for (int k = 0; k < 128; k++){
    float av[4], bv[4];
#pragma unroll
    for (int e = 0; e < 4; e++){ av[e] = Wl[k*64 + ty + e*16]; bv[e] = Al[k*64 + tx + e*16]; }
#pragma unroll
    for (int e2 = 0; e2 < 4; e2++)
#pragma unroll
      for (int e = 0; e < 4; e++) acc[e2][e] = fmaf(av[e2], bv[e], acc[e2][e]);
  }
  const float* bias = (mi==0)? bz : (mi==1)? br : bh;
#pragma unroll
  for (int e2 = 0; e2 < 4; e2++){
    int jo = jo0 + ty + e2*16;
    float bv2 = bias[jo & 255];
#pragma unroll
    for (int e = 0; e < 4; e++)
      Xzrh[(size_t)tp*(768*NB) + (size_t)jo*NB + b0 + tx + e*16] = acc[e2][e] + bv2;
  }
}

// ---------------- ximp [t'][i][b] -> out_x[b][i][t] ----------------
__global__ __launch_bounds__(256) void k_tx(const float* __restrict__ ximp, float* __restrict__ out_x,
                                            int C, int TT, int c0){
  __shared__ float ld[64][65];
  int idx = blockIdx.x;
  int tt = idx % TT; int bt = (idx/TT) & 7; int i = idx/(TT*8);
  int lane = threadIdx.x & 63, sub = threadIdx.x >> 6;
  int t0 = tt*64, b0 = bt*64;
  for (int r = sub; r < 64; r += 4){
    int tp = t0 + r;
    if (tp < C) ld[r][lane] = ximp[(size_t)tp*NBI + i*NB + b0 + lane];
  }
  __syncthreads();
  for (int r = sub; r < 64; r += 4){
    int tp = t0 + lane;
    if (tp < C) out_x[(size_t)(b0+r)*NIN*NT + (size_t)i*NT + c0 + tp] = ld[lane][r];
  }
}

// ---------------- K1: z, r, r*h  (GEMV over hdec) ----------------
// grid 512: jq = blk>>3 (4 j's), bt = blk&7 (64 rows). 4 waves = k-quarters.
__global__ __launch_bounds__(256) void k1(const float* __restrict__ Whz, const float* __restrict__ Whr,
    const float* __restrict__ hdec, const float* __restrict__ Xz_t,
    float* __restrict__ zbuf, float* __restrict__ rh){
  __shared__ float part[4][64][9];
  int tid = threadIdx.x, lane = tid & 63;
  int kq = __builtin_amdgcn_readfirstlane(tid >> 6);
  int jq = blockIdx.x >> 3, bt = blockIdx.x & 7;
  int j0 = jq*4, b = bt*64 + lane, k0 = kq*64;
  float az[4] = {}, ar[4] = {};
  const float* hp = hdec + (size_t)k0*NB + b;
#pragma unroll 8
  for (int k = 0; k < 64; k++){
    float hd = hp[(size_t)k*NB];
#pragma unroll
    for (int e = 0; e < 4; e++){
      az[e] = fmaf(hd, Whz[(size_t)(j0+e)*NH + k0 + k], az[e]);
      ar[e] = fmaf(hd, Whr[(size_t)(j0+e)*NH + k0 + k], ar[e]);
    }
  }
#pragma unroll
  for (int e = 0; e < 4; e++){ part[kq][lane][e*2] = az[e]; part[kq][lane][e*2+1] = ar[e]; }
  __syncthreads();
  int j = j0 + kq;
  float zs = 0.f, rs = 0.f;
#pragma unroll
  for (int q = 0; q < 4; q++){ zs += part[q][lane][kq*2]; rs += part[q][lane][kq*2+1]; }
  float xz = Xz_t[(size_t)j*NB + b];
  float xr = Xz_t[(size_t)(NH + j)*NB + b];
  float hdo = hdec[(size_t)j*NB + b];
  float z = sigm(zs + xz), r = sigm(rs + xr);
  zbuf[(size_t)j*NB + b] = z;
  rh[(size_t)j*NB + b] = r * hdo;
}

// ---------------- K2: h_tilde, h_pre, BN partials (deterministic per-bt) ----------------
__global__ __launch_bounds__(256) void k2(const float* __restrict__ Whh, const float* __restrict__ rh,
    const float* __restrict__ hdec, const float* __restrict__ Xz_t, const float* __restrict__ zbuf,
    float* __restrict__ hpre, float* __restrict__ pbuf){
  __shared__ float part[4][64][5];
  int tid = threadIdx.x, lane = tid & 63;
  int kq = __builtin_amdgcn_readfirstlane(tid >> 6);
  int jq = blockIdx.x >> 3, bt = blockIdx.x & 7;
  int j0 = jq*4, b = bt*64 + lane, k0 = kq*64;
  float ah[4] = {};
  const float* rp = rh + (size_t)k0*NB + b;
#pragma unroll 8
  for (int k = 0; k < 64; k++){
    float rv = rp[(size_t)k*NB];
#pragma unroll
    for (int e = 0; e < 4; e++) ah[e] = fmaf(rv, Whh[(size_t)(j0+e)*NH + k0 + k], ah[e]);
  }
#pragma unroll
  for (int e = 0; e < 4; e++) part[kq][lane][e] = ah[e];
  __syncthreads();
  int j = j0 + kq;
  float hs = 0.f;
#pragma unroll
  for (int q = 0; q < 4; q++) hs += part[q][lane][kq];
  float xh = Xz_t[(size_t)(2*NH + j)*NB + b];
  float ht = tanh_fast(hs + xh);
  float z  = zbuf[(size_t)j*NB + b];
  float hdo = hdec[(size_t)j*NB + b];
  float hp2 = (1.f - z)*hdo + z*ht;
  hpre[(size_t)j*NB + b] = hp2;
  float s1 = wred(hp2);
  float s2 = wred(hp2*hp2);
  if (lane == 0){
    pbuf[((size_t)bt*NH + j)*2]     = s1;
    pbuf[((size_t)bt*NH + j)*2 + 1] = s2;
  }
}

// ---------------- K3: BN finalize, write out_h (transposed), next hdec ----------------
// grid 32: kt = blk>>3, bt = blk&7 ; 64k x 64b tile
__global__ __launch_bounds__(256) void k3(const float* __restrict__ hpre, const float* __restrict__ pbuf,
    const float* __restrict__ gamma, const float* __restrict__ beta,
    const float* __restrict__ gh_next, float* __restrict__ hdec, float* __restrict__ hbn,
    float* __restrict__ outh_t){
  __shared__ float ld[64][65];
  __shared__ float acb[64][2];
  int tid = threadIdx.x;
  int kt = blockIdx.x >> 3, bt = blockIdx.x & 7;
  if (tid < 64){
    int k = kt*64 + tid;
    float s1 = 0.f, s2 = 0.f;
#pragma unroll
    for (int g = 0; g < 8; g++){ s1 += pbuf[((size_t)g*NH + k)*2]; s2 += pbuf[((size_t)g*NH + k)*2 + 1]; }
    float mu = s1*(1.f/NB);
    float var = s2*(1.f/NB) - mu*mu;
    float a = gamma[k]*rsqrtf(var + 1e-5f);
    acb[tid][0] = a;
    acb[tid][1] = beta[k] - a*mu;
  }
  __syncthreads();
#pragma unroll
  for (int p = 0; p < 16; p++){
    int e = p*256 + tid; int kk = e >> 6, bb = e & 63;
    int k = kt*64 + kk, b = bt*64 + bb;
    float hb = fmaf(acb[kk][0], hpre[(size_t)k*NB + b], acb[kk][1]);
    hbn[(size_t)k*NB + b] = hb;
    if (gh_next) hdec[(size_t)k*NB + b] = gh_next[(size_t)k*NB + b]*hb;
    ld[kk][bb] = hb;
  }
  __syncthreads();
#pragma unroll
  for (int p = 0; p < 16; p++){
    int e = p*256 + tid; int bb = e >> 6, kk = e & 63;
    outh_t[(size_t)(bt*64 + bb)*NT*NH + kt*64 + kk] = ld[kk][bb];
  }
}

// ---------------- chunk-boundary hdec = gh[0]*hbn ----------------
__global__ void k_hdec(const float* __restrict__ gh0, const float* __restrict__ hbn, float* __restrict__ hdec){
  int i = blockIdx.x*256 + threadIdx.x;
  if (i < NBH) hdec[i] = gh0[i]*hbn[i];
}

// ---------------- y head: one wave per (b,t) ----------------
__global__ __launch_bounds__(256) void k_y(const float* __restrict__ h, const float* __restrict__ w_hy,
                                           const float* __restrict__ b_hy, float* __restrict__ y){
  int lane = threadIdx.x & 63;
  int gid = blockIdx.x*4 + (threadIdx.x >> 6);
  int b = gid / NT, t = gid % NT;
  const float* hp = h + (size_t)b*NT*NH + (size_t)t*NH + lane;
  float a0 = 0.f, a1 = 0.f;
#pragma unroll
  for (int m = 0; m < 4; m++){
    float hv = hp[m*64];
    a0 = fmaf(hv, w_hy[lane + m*64], a0);
    a1 = fmaf(hv, w_hy[NH + lane + m*64], a1);
  }
  a0 = wred(a0); a1 = wred(a1);
  if (lane == 0){
    y[(size_t)b*NT*NO + t*NO + 0] = sigm(a0 + b_hy[0]);
    y[(size_t)b*NT*NO + t*NO + 1] = sigm(a1 + b_hy[1]);
  }
}

__global__ void k_mask(const float* __restrict__ in, float* __restrict__ om){
  int b = blockIdx.x;
  const float4* src = reinterpret_cast<const float4*>(in + ((size_t)b*3 + 1)*NIN*NT);
  float4* dst = reinterpret_cast<float4*>(om + (size_t)b*NIN*NT);
  for (int r = threadIdx.x; r < NIN*NT/4; r += 256) dst[r] = src[r];
}

extern "C" void kernel_launch(void* const* d_in, const int* in_sizes, int n_in,
                              void* d_out, int out_size, void* d_ws, size_t ws_size,
                              hipStream_t stream){
  (void)in_sizes; (void)n_in; (void)out_size;
  const float* input  = (const float*)d_in[0];
  const float* x_mean = (const float*)d_in[1];
  const float* w_dg_x = (const float*)d_in[2];  const float* b_dg_x = (const float*)d_in[3];
  const float* w_dg_h = (const float*)d_in[4];  const float* b_dg_h = (const float*)d_in[5];
  const float* w_xz = (const float*)d_in[6];    const float* w_hz = (const float*)d_in[7];
  const float* w_mz = (const float*)d_in[8];    const float* b_z  = (const float*)d_in[9];
  const float* w_xr = (const float*)d_in[10];   const float* w_hr = (const float*)d_in[11];
  const float* w_mr = (const float*)d_in[12];   const float* b_r  = (const float*)d_in[13];
  const float* w_xh = (const float*)d_in[14];   const float* w_hh = (const float*)d_in[15];
  const float* w_mh = (const float*)d_in[16];   const float* b_h  = (const float*)d_in[17];
  const float* w_hy = (const float*)d_in[18];   const float* b_hy = (const float*)d_in[19];
  const float* bn_gamma = (const float*)d_in[20];
  const float* bn_beta  = (const float*)d_in[21];

  float* out   = (float*)d_out;
  float* out_y = out;
  float* out_h = out + (size_t)NB*NT*NO;
  float* out_x = out_h + (size_t)NB*NT*NH;
  float* out_m = out_x + (size_t)NB*NIN*NT;

  float* ws = (float*)d_ws;
  size_t off = 0;
  float* hdec = ws + off; off += NBH;
  float* rh   = ws + off; off += NBH;
  float* zbuf = ws + off; off += NBH;
  float* hpre = ws + off; off += NBH;
  float* hbn  = ws + off; off += NBH;
  float* xlast= ws + off; off += NBI;
  float* pbuf = ws + off; off += 8*NH*2;
  float* Wgt  = ws + off; off += 64*320;
  float* W2t  = ws + off; off += 128*768;

  static const int ctab[] = {200,100,50,40,25,20,10,8,5,4,2,1};
  int C = 1;
  for (int i = 0; i < 12; i++){
    size_t need = (off + (size_t)688128*ctab[i])*sizeof(float);
    if (need <= ws_size){ C = ctab[i]; break; }
  }
  float* Xt   = ws + off; off += (size_t)NBI*C;
  float* Mt   = ws + off; off += (size_t)NBI*C;
  float* Dt   = ws + off; off += (size_t)NBI*C;
  float* gx   = ws + off; off += (size_t)NBI*C;
  float* ximp = ws + off; off += (size_t)NBI*C;
  float* gh   = ws + off; off += (size_t)NBH*C;
  float* Xzrh = ws + off; off += (size_t)768*NB*C;

  hipLaunchKernelGGL(k_init, dim3((NBH+255)/256), dim3(256), 0, stream, hdec);
  hipLaunchKernelGGL(k_wprep, dim3((320*64 + 768*128 + 255)/256), dim3(256), 0, stream,
                     w_dg_x, w_dg_h, w_xz, w_xr, w_xh, w_mz, w_mr, w_mh, Wgt, W2t);

  int TT = (C + 63)/64;
  int nch = NT / C;
  for (int c = 0; c < nch; c++){
    int c0 = c*C;
    hipLaunchKernelGGL(k_tin, dim3(3*64*8*TT), dim3(256), 0, stream, input, Xt, Mt, Dt, C, TT, c0);
    hipLaunchKernelGGL(k_g1,  dim3(C*40), dim3(256), 0, stream, Wgt, Dt, b_dg_x, b_dg_h, gx, gh);
    if (c > 0) hipLaunchKernelGGL(k_hdec, dim3((NBH+255)/256), dim3(256), 0, stream, gh, hbn, hdec);
    hipLaunchKernelGGL(k_scan, dim3(128), dim3(256), 0, stream, Xt, Mt, gx, x_mean, xlast, ximp, C, c==0 ? 1 : 0);
    hipLaunchKernelGGL(k_g2,  dim3(C*96), dim3(256), 0, stream, W2t, ximp, Mt, b_z, b_r, b_h, Xzrh);
    hipLaunchKernelGGL(k_tx,  dim3(64*8*TT), dim3(256), 0, stream, ximp, out_x, C, TT, c0);
    for (int tp = 0; tp < C; tp++){
      int t = c0 + tp;
      const float* Xz_t = Xzrh + (size_t)tp*768*NB;
      hipLaunchKernelGGL(k1, dim3(512), dim3(256), 0, stream, w_hz, w_hr, hdec, Xz_t, zbuf, rh);
      hipLaunchKernelGGL(k2, dim3(512), dim3(256), 0, stream, w_hh, rh, hdec, Xz_t, zbuf, hpre, pbuf);
      const float* ghn = (tp < C-1) ? (gh + (size_t)(tp+1)*NBH) : nullptr;
      hipLaunchKernelGGL(k3, dim3(32), dim3(256), 0, stream, hpre, pbuf, bn_gamma, bn_beta,
                         ghn, hdec, hbn, out_h + (size_t)t*NH);
    }
  }
  hipLaunchKernelGGL(k_y, dim3(NB*NT/4), dim3(256), 0, stream, out_h, w_hy, b_hy, out_y);
  hipLaunchKernelGGL(k_mask, dim3(NB), dim3(256), 0, stream, input, out_m);
}

// Round 3
// 3798.243 us; speedup vs baseline: 10.3252x; 1.5635x over previous
//
#include <hip/hip_runtime.h>

#define NB 512
#define NIN 64
#define NH 256
#define NT 200
#define NO 2
#define NBI (NB*NIN)    // 32768  one [i][b] plane
#define NBH (NB*NH)     // 131072 one [k][b] plane

__device__ __forceinline__ float sigm(float x){ return 1.f/(1.f+__expf(-x)); }
__device__ __forceinline__ float tanh_fast(float x){ return 2.f/(1.f+__expf(-2.f*x)) - 1.f; }
__device__ __forceinline__ float wred(float v){
#pragma unroll
  for (int off=32; off>0; off>>=1) v += __shfl_xor(v, off, 64);
  return v;
}

// ---------------- one-time weight transposes ----------------
__global__ void k_wprep(const float* __restrict__ w_dg_x, const float* __restrict__ w_dg_h,
                        const float* __restrict__ w_xz, const float* __restrict__ w_xr, const float* __restrict__ w_xh,
                        const float* __restrict__ w_mz, const float* __restrict__ w_mr, const float* __restrict__ w_mh,
                        float* __restrict__ Wgt, float* __restrict__ W2t){
  int idx = blockIdx.x*256 + threadIdx.x;
  if (idx < 320*64){
    int io = idx % 320, k = idx / 320;
    Wgt[k*320 + io] = (io < 64) ? w_dg_x[io*NIN + k] : w_dg_h[(io-64)*NIN + k];
  } else if (idx < 320*64 + 768*128){
    int j2 = idx - 320*64;
    int jo = j2 % 768, k = j2 / 768;
    int mi = jo >> 8, jr = jo & 255;
    const float* WX = (mi==0)? w_xz : (mi==1)? w_xr : w_xh;
    const float* WM = (mi==0)? w_mz : (mi==1)? w_mr : w_mh;
    W2t[k*768 + jo] = (k < 64) ? WX[jr*NIN + k] : WM[jr*NIN + (k-64)];
  }
}

// ---------------- input transpose: (B,3,IN,T) slice -> [t'][i][b] ----------------
__global__ __launch_bounds__(256) void k_tin(const float* __restrict__ in,
    float* __restrict__ Xt, float* __restrict__ Mt, float* __restrict__ Dt,
    int C, int TT, int c0){
  __shared__ float ld[64][65];
  int idx = blockIdx.x;
  int tt = idx % TT; int bt = (idx/TT) & 7; int i = (idx/(TT*8)) & 63; int c = idx/(TT*8*64);
  float* dst = (c==0)? Xt : (c==1)? Mt : Dt;
  int lane = threadIdx.x & 63, sub = threadIdx.x >> 6;
  int t0 = tt*64, b0 = bt*64;
  for (int r = sub; r < 64; r += 4){
    int tp = t0 + lane;
    if (tp < C) ld[r][lane] = in[((size_t)(b0+r)*3 + c)*NIN*NT + (size_t)i*NT + c0 + tp];
  }
  __syncthreads();
  for (int r = sub; r < 64; r += 4){
    int tp = t0 + r;
    if (tp < C) dst[(size_t)tp*NBI + i*NB + b0 + lane] = ld[lane][r];
  }
}

// ---------------- G1: gamma GEMM. out = exp(-relu(W*d + bias)) ----------------
__global__ __launch_bounds__(256) void k_g1(const float* __restrict__ Wgt, const float* __restrict__ Dt,
    const float* __restrict__ b_dg_x, const float* __restrict__ b_dg_h,
    float* __restrict__ gx, float* __restrict__ gh){
  __shared__ float Wl[64*64];   // [k][io]
  __shared__ float Dl[64*64];   // [k][b]
  int idx = blockIdx.x;
  int bt = idx & 7, io5 = (idx>>3) % 5, tp = idx / 40;
  int b0 = bt*64, io0 = io5*64;
  int tid = threadIdx.x, tx = tid & 15, ty = tid >> 4;
  for (int f = tid; f < 1024; f += 256){
    int k = f >> 4, seg = f & 15;
    *(float4*)&Wl[k*64 + seg*4] = *(const float4*)&Wgt[k*320 + io0 + seg*4];
    *(float4*)&Dl[k*64 + seg*4] = *(const float4*)&Dt[(size_t)tp*NBI + k*NB + b0 + seg*4];
  }
  __syncthreads();
  float acc[4][4] = {};
#pragma unroll 4
  for (int k = 0; k < 64; k++){
    float av[4], bv[4];
#pragma unroll
    for (int e = 0; e < 4; e++){ av[e] = Wl[k*64 + ty + e*16]; bv[e] = Dl[k*64 + tx + e*16]; }
#pragma unroll
    for (int e2 = 0; e2 < 4; e2++)
#pragma unroll
      for (int e = 0; e < 4; e++) acc[e2][e] = fmaf(av[e2], bv[e], acc[e2][e]);
  }
#pragma unroll
  for (int e2 = 0; e2 < 4; e2++){
    int io = io0 + ty + e2*16;
    float bias = (io < 64) ? b_dg_x[io] : b_dg_h[io-64];
#pragma unroll
    for (int e = 0; e < 4; e++){
      float v = __expf(-fmaxf(acc[e2][e] + bias, 0.f));
      int b = b0 + tx + e*16;
      if (io < 64) gx[(size_t)tp*NBI + io*NB + b] = v;
      else         gh[(size_t)tp*NBH + (size_t)(io-64)*NB + b] = v;
    }
  }
}

// ---------------- imputation scan over chunk ----------------
__global__ void k_scan(const float* __restrict__ Xt, const float* __restrict__ Mt,
                       const float* __restrict__ gx, const float* __restrict__ x_mean,
                       float* __restrict__ xlast, float* __restrict__ ximp, int C, int first){
  int gi = blockIdx.x*256 + threadIdx.x;
  int i = gi >> 9;
  float xl = first ? 0.f : xlast[gi];
  float xm = x_mean[i];
  for (int t = 0; t < C; t++){
    size_t o = (size_t)t*NBI + gi;
    float x = Xt[o], m = Mt[o], g = gx[o];
    xl = (m > 0.f) ? x : xl;
    ximp[o] = m*x + (1.f-m)*(g*xl + (1.f-g)*xm);
  }
  xlast[gi] = xl;
}

// ---------------- G2: Xzrh[t'][jo][b] = W2*[ximp;m] + bias ----------------
__global__ __launch_bounds__(256) void k_g2(const float* __restrict__ W2t, const float* __restrict__ ximp,
    const float* __restrict__ Mt, const float* __restrict__ bz, const float* __restrict__ br,
    const float* __restrict__ bh, float* __restrict__ Xzrh){
  __shared__ float smem[16384];
  float* Wl = smem; float* Al = smem + 8192;
  int idx = blockIdx.x;
  int bt = idx & 7, jt = (idx>>3) % 12, tp = idx / 96;
  int b0 = bt*64, jo0 = jt*64, mi = jt >> 2;
  int tid = threadIdx.x, tx = tid & 15, ty = tid >> 4;
  for (int f = tid; f < 2048; f += 256){
    int k = f >> 4, seg = f & 15;
    *(float4*)&Wl[k*64 + seg*4] = *(const float4*)&W2t[k*768 + jo0 + seg*4];
    const float* src = (k < 64) ? (ximp + (size_t)tp*NBI + k*NB) : (Mt + (size_t)tp*NBI + (size_t)(k-64)*NB);
    *(float4*)&Al[k*64 + seg*4] = *(const float4*)&src[b0 + seg*4];
  }
  __syncthreads();
  float acc[4][4] = {};
#pragma unroll 4
  for (int k = 0; k < 128; k++){
    float av[4], bv[4];
#pragma unroll
    for (int e = 0; e < 4; e++){ av[e] = Wl[k*64 + ty + e*16]; bv[e] = Al[k*64 + tx + e*16]; }
#pragma unroll
    for (int e2 = 0; e2 < 4; e2++)
#pragma unroll
      for (int e = 0; e < 4; e++) acc[e2][e] = fmaf(av[e2], bv[e], acc[e2][e]);
  }
  const float* bias = (mi==0)? bz : (mi==1)? br : bh;
#pragma unroll
  for (int e2 = 0; e2 < 4; e2++){
    int jo = jo0 + ty + e2*16;
    float bv2 = bias[jo & 255];
#pragma unroll
    for (int e = 0; e < 4; e++)
      Xzrh[(size_t)tp*(768*NB) + (size_t)jo*NB + b0 + tx + e*16] = acc[e2][e] + bv2;
  }
}

// ---------------- ximp [t'][i][b] -> out_x[b][i][t] ----------------
__global__ __launch_bounds__(256) void k_tx(const float* __restrict__ ximp, float* __restrict__ out_x,
                                            int C, int TT, int c0){
  __shared__ float ld[64][65];
  int idx = blockIdx.x;
  int tt = idx % TT; int bt = (idx/TT) & 7; int i = idx/(TT*8);
  int lane = threadIdx.x & 63, sub = threadIdx.x >> 6;
  int t0 = tt*64, b0 = bt*64;
  for (int r = sub; r < 64; r += 4){
    int tp = t0 + r;
    if (tp < C) ld[r][lane] = ximp[(size_t)tp*NBI + i*NB + b0 + lane];
  }
  __syncthreads();
  for (int r = sub; r < 64; r += 4){
    int tp = t0 + lane;
    if (tp < C) out_x[(size_t)(b0+r)*NIN*NT + (size_t)i*NT + c0 + tp] = ld[lane][r];
  }
}

// ---------------- K1: BN-finalize(t-1) + z,r + out_h(t-1) ----------------
// grid 512: jq = blk>>3 (4 j's), bt = blk&7. 4 waves = k-quarters.
// hdec(t)[k][b] = gh(t)[k][b] * (a[k]*hpre(t-1)[k][b] + c[k]) reconstructed on the fly.
template<int FIRST>
__global__ __launch_bounds__(256) void k1(const float* __restrict__ Whz, const float* __restrict__ Whr,
    const float* __restrict__ gh_t, const float* __restrict__ hpre, const float* __restrict__ pbuf,
    const float* __restrict__ gamma, const float* __restrict__ beta,
    const float* __restrict__ Xz_t, float* __restrict__ zbuf, float* __restrict__ rh,
    float* __restrict__ hdb, float* __restrict__ out_h, int t){
  __shared__ float acb[256][2];
  __shared__ float part[4][64][9];
  int tid = threadIdx.x, lane = tid & 63;
  int kq = __builtin_amdgcn_readfirstlane(tid >> 6);
  int jq = blockIdx.x >> 3, bt = blockIdx.x & 7;
  int j0 = jq*4, b = bt*64 + lane;

  if (!FIRST){
    int k = tid;
    float s1 = 0.f, s2 = 0.f;
#pragma unroll
    for (int g = 0; g < 8; g++){ s1 += pbuf[((size_t)g*NH + k)*2]; s2 += pbuf[((size_t)g*NH + k)*2 + 1]; }
    float mu = s1*(1.f/NB);
    float var = s2*(1.f/NB) - mu*mu;
    float a = gamma[k]*rsqrtf(var + 1e-5f);
    acb[k][0] = a;
    acb[k][1] = beta[k] - a*mu;
    __syncthreads();
  }

  float az[4] = {}, ar[4] = {};
  if (!FIRST){
    const float* ghp = gh_t + (size_t)(kq*64)*NB + b;
    const float* hpp = hpre + (size_t)(kq*64)*NB + b;
#pragma unroll 8
    for (int kk = 0; kk < 64; kk++){
      int k = kq*64 + kk;
      float hb = fmaf(acb[k][0], hpp[(size_t)kk*NB], acb[k][1]);
      float hd = ghp[(size_t)kk*NB]*hb;
#pragma unroll
      for (int e = 0; e < 4; e++){
        az[e] = fmaf(hd, Whz[(size_t)(j0+e)*NH + k], az[e]);
        ar[e] = fmaf(hd, Whr[(size_t)(j0+e)*NH + k], ar[e]);
      }
    }
    // out_h(t-1): this wave owns k-row ko = kq*64 + jq
    int ko = kq*64 + jq;
    float hbo = fmaf(acb[ko][0], hpre[(size_t)ko*NB + b], acb[ko][1]);
    out_h[(size_t)b*NT*NH + (size_t)(t-1)*NH + ko] = hbo;
  }
#pragma unroll
  for (int e = 0; e < 4; e++){ part[kq][lane][e*2] = az[e]; part[kq][lane][e*2+1] = ar[e]; }
  __syncthreads();
  int j = j0 + kq;
  float zs = 0.f, rs = 0.f;
#pragma unroll
  for (int q = 0; q < 4; q++){ zs += part[q][lane][kq*2]; rs += part[q][lane][kq*2+1]; }
  float hdo;
  if (FIRST) hdo = 0.f;
  else       hdo = gh_t[(size_t)j*NB + b]*fmaf(acb[j][0], hpre[(size_t)j*NB + b], acb[j][1]);
  float z = sigm(zs + Xz_t[(size_t)j*NB + b]);
  float r = sigm(rs + Xz_t[(size_t)(NH + j)*NB + b]);
  zbuf[(size_t)j*NB + b] = z;
  rh[(size_t)j*NB + b]   = r*hdo;
  hdb[(size_t)j*NB + b]  = hdo;
}

// ---------------- K2: h_tilde, h_pre, BN partials ----------------
__global__ __launch_bounds__(256) void k2(const float* __restrict__ Whh, const float* __restrict__ rh,
    const float* __restrict__ hdb, const float* __restrict__ Xz_t, const float* __restrict__ zbuf,
    float* __restrict__ hpre, float* __restrict__ pbuf){
  __shared__ float part[4][64][5];
  int tid = threadIdx.x, lane = tid & 63;
  int kq = __builtin_amdgcn_readfirstlane(tid >> 6);
  int jq = blockIdx.x >> 3, bt = blockIdx.x & 7;
  int j0 = jq*4, b = bt*64 + lane, k0 = kq*64;
  float ah[4] = {};
  const float* rp = rh + (size_t)k0*NB + b;
#pragma unroll 8
  for (int k = 0; k < 64; k++){
    float rv = rp[(size_t)k*NB];
#pragma unroll
    for (int e = 0; e < 4; e++) ah[e] = fmaf(rv, Whh[(size_t)(j0+e)*NH + k0 + k], ah[e]);
  }
#pragma unroll
  for (int e = 0; e < 4; e++) part[kq][lane][e] = ah[e];
  __syncthreads();
  int j = j0 + kq;
  float hs = 0.f;
#pragma unroll
  for (int q = 0; q < 4; q++) hs += part[q][lane][kq];
  float xh = Xz_t[(size_t)(2*NH + j)*NB + b];
  float ht = tanh_fast(hs + xh);
  float z  = zbuf[(size_t)j*NB + b];
  float hdo = hdb[(size_t)j*NB + b];
  float hp2 = (1.f - z)*hdo + z*ht;
  hpre[(size_t)j*NB + b] = hp2;
  float s1 = wred(hp2);
  float s2 = wred(hp2*hp2);
  if (lane == 0){
    pbuf[((size_t)bt*NH + j)*2]     = s1;
    pbuf[((size_t)bt*NH + j)*2 + 1] = s2;
  }
}

// ---------------- final out_h(NT-1) ----------------
__global__ __launch_bounds__(256) void k3f(const float* __restrict__ hpre, const float* __restrict__ pbuf,
    const float* __restrict__ gamma, const float* __restrict__ beta, float* __restrict__ out_h){
  __shared__ float ld[64][65];
  __shared__ float acb[64][2];
  int tid = threadIdx.x;
  int kt = blockIdx.x >> 3, bt = blockIdx.x & 7;
  if (tid < 64){
    int k = kt*64 + tid;
    float s1 = 0.f, s2 = 0.f;
#pragma unroll
    for (int g = 0; g < 8; g++){ s1 += pbuf[((size_t)g*NH + k)*2]; s2 += pbuf[((size_t)g*NH + k)*2 + 1]; }
    float mu = s1*(1.f/NB);
    float var = s2*(1.f/NB) - mu*mu;
    float a = gamma[k]*rsqrtf(var + 1e-5f);
    acb[tid][0] = a;
    acb[tid][1] = beta[k] - a*mu;
  }
  __syncthreads();
#pragma unroll
  for (int p = 0; p < 16; p++){
    int e = p*256 + tid; int kk = e >> 6, bb = e & 63;
    int k = kt*64 + kk, b = bt*64 + bb;
    ld[kk][bb] = fmaf(acb[kk][0], hpre[(size_t)k*NB + b], acb[kk][1]);
  }
  __syncthreads();
#pragma unroll
  for (int p = 0; p < 16; p++){
    int e = p*256 + tid; int bb = e >> 6, kk = e & 63;
    out_h[(size_t)(bt*64 + bb)*NT*NH + (size_t)(NT-1)*NH + kt*64 + kk] = ld[kk][bb];
  }
}

// ---------------- y head ----------------
__global__ __launch_bounds__(256) void k_y(const float* __restrict__ h, const float* __restrict__ w_hy,
                                           const float* __restrict__ b_hy, float* __restrict__ y){
  int lane = threadIdx.x & 63;
  int gid = blockIdx.x*4 + (threadIdx.x >> 6);
  int b = gid / NT, t = gid % NT;
  const float* hp = h + (size_t)b*NT*NH + (size_t)t*NH + lane;
  float a0 = 0.f, a1 = 0.f;
#pragma unroll
  for (int m = 0; m < 4; m++){
    float hv = hp[m*64];
    a0 = fmaf(hv, w_hy[lane + m*64], a0);
    a1 = fmaf(hv, w_hy[NH + lane + m*64], a1);
  }
  a0 = wred(a0); a1 = wred(a1);
  if (lane == 0){
    y[(size_t)b*NT*NO + t*NO + 0] = sigm(a0 + b_hy[0]);
    y[(size_t)b*NT*NO + t*NO + 1] = sigm(a1 + b_hy[1]);
  }
}

__global__ void k_mask(const float* __restrict__ in, float* __restrict__ om){
  int b = blockIdx.x;
  const float4* src = reinterpret_cast<const float4*>(in + ((size_t)b*3 + 1)*NIN*NT);
  float4* dst = reinterpret_cast<float4*>(om + (size_t)b*NIN*NT);
  for (int r = threadIdx.x; r < NIN*NT/4; r += 256) dst[r] = src[r];
}

extern "C" void kernel_launch(void* const* d_in, const int* in_sizes, int n_in,
                              void* d_out, int out_size, void* d_ws, size_t ws_size,
                              hipStream_t stream){
  (void)in_sizes; (void)n_in; (void)out_size;
  const float* input  = (const float*)d_in[0];
  const float* x_mean = (const float*)d_in[1];
  const float* w_dg_x = (const float*)d_in[2];  const float* b_dg_x = (const float*)d_in[3];
  const float* w_dg_h = (const float*)d_in[4];  const float* b_dg_h = (const float*)d_in[5];
  const float* w_xz = (const float*)d_in[6];    const float* w_hz = (const float*)d_in[7];
  const float* w_mz = (const float*)d_in[8];    const float* b_z  = (const float*)d_in[9];
  const float* w_xr = (const float*)d_in[10];   const float* w_hr = (const float*)d_in[11];
  const float* w_mr = (const float*)d_in[12];   const float* b_r  = (const float*)d_in[13];
  const float* w_xh = (const float*)d_in[14];   const float* w_hh = (const float*)d_in[15];
  const float* w_mh = (const float*)d_in[16];   const float* b_h  = (const float*)d_in[17];
  const float* w_hy = (const float*)d_in[18];   const float* b_hy = (const float*)d_in[19];
  const float* bn_gamma = (const float*)d_in[20];
  const float* bn_beta  = (const float*)d_in[21];

  float* out   = (float*)d_out;
  float* out_y = out;
  float* out_h = out + (size_t)NB*NT*NO;
  float* out_x = out_h + (size_t)NB*NT*NH;
  float* out_m = out_x + (size_t)NB*NIN*NT;

  float* ws = (float*)d_ws;
  size_t off = 0;
  float* hpre = ws + off; off += NBH;
  float* zbuf = ws + off; off += NBH;
  float* rh   = ws + off; off += NBH;
  float* hdb  = ws + off; off += NBH;
  float* xlast= ws + off; off += NBI;
  float* pbuf = ws + off; off += 8*NH*2;
  float* Wgt  = ws + off; off += 64*320;
  float* W2t  = ws + off; off += 128*768;

  static const int ctab[] = {200,100,50,40,25,20,10,8,5,4,2,1};
  int C = 1;
  for (int i = 0; i < 12; i++){
    size_t need = (off + (size_t)688128*ctab[i])*sizeof(float);
    if (need <= ws_size){ C = ctab[i]; break; }
  }
  float* Xt   = ws + off; off += (size_t)NBI*C;
  float* Mt   = ws + off; off += (size_t)NBI*C;
  float* Dt   = ws + off; off += (size_t)NBI*C;
  float* gx   = ws + off; off += (size_t)NBI*C;
  float* ximp = ws + off; off += (size_t)NBI*C;
  float* gh   = ws + off; off += (size_t)NBH*C;
  float* Xzrh = ws + off; off += (size_t)768*NB*C;

  hipLaunchKernelGGL(k_wprep, dim3((320*64 + 768*128 + 255)/256), dim3(256), 0, stream,
                     w_dg_x, w_dg_h, w_xz, w_xr, w_xh, w_mz, w_mr, w_mh, Wgt, W2t);

  int TT = (C + 63)/64;
  int nch = NT / C;
  for (int c = 0; c < nch; c++){
    int c0 = c*C;
    hipLaunchKernelGGL(k_tin, dim3(3*64*8*TT), dim3(256), 0, stream, input, Xt, Mt, Dt, C, TT, c0);
    hipLaunchKernelGGL(k_g1,  dim3(C*40), dim3(256), 0, stream, Wgt, Dt, b_dg_x, b_dg_h, gx, gh);
    hipLaunchKernelGGL(k_scan, dim3(128), dim3(256), 0, stream, Xt, Mt, gx, x_mean, xlast, ximp, C, c==0 ? 1 : 0);
    hipLaunchKernelGGL(k_g2,  dim3(C*96), dim3(256), 0, stream, W2t, ximp, Mt, b_z, b_r, b_h, Xzrh);
    hipLaunchKernelGGL(k_tx,  dim3(64*8*TT), dim3(256), 0, stream, ximp, out_x, C, TT, c0);
    for (int tp = 0; tp < C; tp++){
      int t = c0 + tp;
      const float* Xz_t = Xzrh + (size_t)tp*768*NB;
      const float* gh_t = gh + (size_t)tp*NBH;
      if (t == 0)
        hipLaunchKernelGGL(k1<1>, dim3(512), dim3(256), 0, stream, w_hz, w_hr, gh_t, hpre, pbuf,
                           bn_gamma, bn_beta, Xz_t, zbuf, rh, hdb, out_h, t);
      else
        hipLaunchKernelGGL(k1<0>, dim3(512), dim3(256), 0, stream, w_hz, w_hr, gh_t, hpre, pbuf,
                           bn_gamma, bn_beta, Xz_t, zbuf, rh, hdb, out_h, t);
      hipLaunchKernelGGL(k2, dim3(512), dim3(256), 0, stream, w_hh, rh, hdb, Xz_t, zbuf, hpre, pbuf);
    }
  }
  hipLaunchKernelGGL(k3f, dim3(32), dim3(256), 0, stream, hpre, pbuf, bn_gamma, bn_beta, out_h);
  hipLaunchKernelGGL(k_y, dim3(NB*NT/4), dim3(256), 0, stream, out_h, w_hy, b_hy, out_y);
  hipLaunchKernelGGL(k_mask, dim3(NB), dim3(256), 0, stream, input, out_m);
}